// Round 6
// baseline (276.235 us; speedup 1.0000x reference)
//
#include <hip/hip_runtime.h>

typedef __bf16 bf16x8 __attribute__((ext_vector_type(8)));
typedef float  f32x4  __attribute__((ext_vector_type(4)));

#define NROWS 8192
#define DK    4096
#define MCOLS 4096
#define NKT   64            // K-tiles of BK=64
#define IMG   16384         // bf16 elems per 256x64 tile image (32 KB)
#define X_TILES 32
#define W_TILES 16

#define X_ELEMS ((size_t)NROWS * DK)
#define A_ELEMS ((size_t)MCOLS * DK)
#define WS_NEED ((X_ELEMS + A_ELEMS) * 2)

#define BAR()  do { __builtin_amdgcn_s_barrier(); asm volatile("" ::: "memory"); } while (0)
#define VM(n)  asm volatile("s_waitcnt vmcnt(" #n ")" ::: "memory")

__device__ __forceinline__ bf16x8 pack8(const float4& a, const float4& b) {
  bf16x8 r;
  r[0] = (__bf16)a.x; r[1] = (__bf16)a.y; r[2] = (__bf16)a.z; r[3] = (__bf16)a.w;
  r[4] = (__bf16)b.x; r[5] = (__bf16)b.y; r[6] = (__bf16)b.z; r[7] = (__bf16)b.w;
  return r;
}

__device__ __forceinline__ void gload16(const __bf16* g, __bf16* l) {
  __builtin_amdgcn_global_load_lds(
      (const __attribute__((address_space(1))) void*)g,
      (__attribute__((address_space(3))) void*)l, 16, 0, 0);
}

// X image: [tm][kt][mfrag 0..15][kc 0..1][lane][8]
// mfrag -> rows tm*256 + mfrag*16 + l15 ; k = kt*64 + kc*32 + lg*8
__global__ __launch_bounds__(256) void convX(const float* __restrict__ src,
                                             __bf16* __restrict__ dst) {
  const int total = X_TILES * NKT * 2048;
  for (int i = blockIdx.x * blockDim.x + threadIdx.x; i < total;
       i += gridDim.x * blockDim.x) {
    int lane = i & 63;
    int kc   = (i >> 6) & 1;
    int mf   = (i >> 7) & 15;
    int kt   = (i >> 11) & 63;
    int tm   = i >> 17;
    int row = tm * 256 + mf * 16 + (lane & 15);
    int k   = kt * 64 + kc * 32 + (lane >> 4) * 8;
    const float4* p = (const float4*)(src + (size_t)row * DK + k);
    float4 a = p[0], b = p[1];
    *(bf16x8*)(dst + (size_t)i * 8) = pack8(a, b);
  }
}

// W image: [tn][kt][r 0..1][s 0..15][lane][8]
// s: kc=s&1, n4=(s>>1)&3, wc2=s>>3 ; nfrag = wc2*8 + r*4 + n4
__global__ __launch_bounds__(256) void convW(const float* __restrict__ src,
                                             __bf16* __restrict__ dst) {
  const int total = W_TILES * NKT * 2048;
  for (int i = blockIdx.x * blockDim.x + threadIdx.x; i < total;
       i += gridDim.x * blockDim.x) {
    int lane = i & 63;
    int s    = (i >> 6) & 15;
    int r    = (i >> 10) & 1;
    int kt   = (i >> 11) & 63;
    int tn   = i >> 17;
    int kc = s & 1, n4 = (s >> 1) & 3, wq = s >> 3;
    int nfrag = wq * 8 + r * 4 + n4;
    int row = tn * 256 + nfrag * 16 + (lane & 15);
    int k   = kt * 64 + kc * 32 + (lane >> 4) * 8;
    const float4* p = (const float4*)(src + (size_t)row * DK + k);
    float4 a = p[0], b = p[1];
    *(bf16x8*)(dst + (size_t)i * 8) = pack8(a, b);
  }
}

// ---- X-in-registers, W 3-deep LDS, 1 barrier/K-tile ------------------------
__global__ __launch_bounds__(512, 2) void gemm9(const __bf16* __restrict__ wsX,
                                                const __bf16* __restrict__ wsW,
                                                float* __restrict__ out) {
  __shared__ __align__(16) __bf16 Wls[3 * IMG];   // 96 KB (3 x 32 KB W-tile)
  __shared__ float rowsum[2][256];

  const int t    = threadIdx.x;
  const int lane = t & 63;
  const int w    = t >> 6;           // 0..7
  const int wr4  = w >> 1;           // rows wr4*64..+63
  const int wc2  = w & 1;            // cols wc2*128..+127
  const int l15  = lane & 15;
  const int lg   = lane >> 4;

  // XCD mapping (R5): each XCD an 8m x 8n region
  unsigned bid = blockIdx.x;
  unsigned xcd = bid & 7, seq = bid >> 3;
  const int tile_m = (int)((xcd >> 1) * 8 + (seq & 7));    // 0..31
  const int tile_n = (int)((xcd & 1) * 8 + (seq >> 3));    // 0..15

  const __bf16* xbase = wsX + (size_t)tile_m * ((size_t)NKT * IMG);
  const __bf16* wbase = wsW + (size_t)tile_n * ((size_t)NKT * IMG);
  // per-wave X fragment base: mfrag = wr4*4 + (MH*2+m2); slot = mfrag*1024 + kc*512
  const __bf16* xw = xbase + (size_t)(wr4 * 4) * 1024 + (size_t)lane * 8;

  f32x4 acc[4][8] = {};
  bf16x8 xa[2][2][2], xb[2][2][2], b[4][2];

  auto loadXset = [&](bf16x8 (&x)[2][2][2], int h) {
    const __bf16* p = xw + (size_t)h * IMG;
#pragma unroll
    for (int MH = 0; MH < 2; ++MH)
#pragma unroll
      for (int m2 = 0; m2 < 2; ++m2)
#pragma unroll
        for (int kc = 0; kc < 2; ++kc)
          x[MH][m2][kc] = *(const bf16x8*)(p + ((MH * 2 + m2) * 2 + kc) * 512);
  };

  auto readB = [&](const __bf16* bufR, int r) {
#pragma unroll
    for (int n4 = 0; n4 < 4; ++n4)
#pragma unroll
      for (int kc = 0; kc < 2; ++kc)
        b[n4][kc] = *(const bf16x8*)(bufR + r * 8192 +
                                     ((wc2 * 4 + n4) * 2 + kc) * 512 + lane * 8);
  };

  auto stageW = [&](const __bf16* src, __bf16* dst) {   // one 8192-elem region
    const __bf16* s0 = src + t * 8;
    __bf16* d0 = dst + w * 512;
    gload16(s0, d0);
    gload16(s0 + 4096, d0 + 4096);
  };

  auto quad = [&](const bf16x8 (&x)[2][2][2], int MH, int NH) {
    __builtin_amdgcn_s_setprio(1);
#pragma unroll
    for (int kc = 0; kc < 2; ++kc)
#pragma unroll
      for (int m2 = 0; m2 < 2; ++m2)
#pragma unroll
        for (int n4 = 0; n4 < 4; ++n4)
          acc[MH * 2 + m2][NH * 4 + n4] = __builtin_amdgcn_mfma_f32_16x16x32_bf16(
              x[MH][m2][kc], b[n4][kc], acc[MH * 2 + m2][NH * 4 + n4], 0, 0, 0);
    __builtin_amdgcn_s_setprio(0);
  };

  // tile body. vmn: 4 = steady VM(4), 0 = tail VM(0), -1 = none.
  auto tile = [&](int h, bf16x8 (&xcur)[2][2][2], bf16x8 (&xnext)[2][2][2],
                  bool do_stage, bool do_loadx, int vmn) {
    __bf16* bufR = Wls + (h % 3) * IMG;
    __bf16* bufS = Wls + ((h + 2) % 3) * IMG;
    const __bf16* wsrc = wbase + (size_t)(h + 2) * IMG;
    // q1
    readB(bufR, 0);
    if (do_stage) stageW(wsrc, bufS);                 // W0(h+2)
    quad(xcur, 0, 0);
    // q2
    readB(bufR, 1);
    if (do_stage) stageW(wsrc + 8192, bufS + 8192);   // W1(h+2)
    quad(xcur, 0, 1);
    // q3
    readB(bufR, 0);
    if (do_loadx) loadXset(xnext, h + 1);
    quad(xcur, 1, 0);
    // q4
    readB(bufR, 1);
    quad(xcur, 1, 1);
    if (vmn == 4) { VM(4); }          // forces W(h+1): 4 newer gloads = W(h+2)
    else if (vmn == 0) { VM(0); }
    BAR();
  };

  // prologue: W(0)->buf0, W(1)->buf1 (FIFO), X(0)->xa
  stageW(wbase,              Wls);
  stageW(wbase + 8192,       Wls + 8192);
  stageW(wbase + IMG,        Wls + IMG);
  stageW(wbase + IMG + 8192, Wls + IMG + 8192);
  loadXset(xa, 0);
  VM(4);                         // forces W(0); W(1)'s 4 gloads are the newest
  BAR();

  for (int h = 0; h < 62; h += 2) {
    tile(h,     xa, xb, true, true, 4);
    tile(h + 1, xb, xa, true, true, 4);
  }
  tile(62, xa, xb, false, true, 0);    // forces W(63)
  tile(63, xb, xa, false, false, -1);

  // ---- epilogue: row sums of squares ----
  float v[4][4];
#pragma unroll
  for (int mr = 0; mr < 4; ++mr)
#pragma unroll
    for (int j = 0; j < 4; ++j) {
      float s = 0.f;
#pragma unroll
      for (int nc = 0; nc < 8; ++nc) {
        float c = acc[mr][nc][j];
        s += c * c;
      }
      s += __shfl_xor(s, 1, 64);
      s += __shfl_xor(s, 2, 64);
      s += __shfl_xor(s, 4, 64);
      s += __shfl_xor(s, 8, 64);
      v[mr][j] = s;
    }

  if (l15 == 0) {
#pragma unroll
    for (int mr = 0; mr < 4; ++mr)
#pragma unroll
      for (int j = 0; j < 4; ++j)
        rowsum[wc2][(wr4 * 4 + mr) * 16 + lg * 4 + j] = v[mr][j];
  }
  __syncthreads();

  if (t < 256) {
    float p = rowsum[0][t] + rowsum[1][t];
    atomicAdd(&out[tile_m * 256 + t], p);
  }
}

// ---------------- fallback (direct fp32 path, used only if ws too small) ----
struct Stage {
  float4 x0a, x0b, x1a, x1b;
  float4 a0a, a0b, a1a, a1b;
};

__global__ __launch_bounds__(256) void gemm_rowsq(const float* __restrict__ X,
                                                  const float* __restrict__ A,
                                                  float* __restrict__ out) {
  __shared__ __align__(16) __bf16 Xs[128 * 32];
  __shared__ __align__(16) __bf16 As[128 * 32];
  __shared__ float rowsum[2][128];

  const int t    = threadIdx.x;
  const int lane = t & 63;
  const int wid  = t >> 6;
  const int wr   = wid >> 1;
  const int wc   = wid & 1;
  const int l15  = lane & 15;
  const int lg   = lane >> 4;

  unsigned bid = blockIdx.x;
  unsigned swz = (bid & 7) * 256u + (bid >> 3);
  const int tile_m = swz >> 5;
  const int tile_n = swz & 31;

  const int srow = t >> 2;
  const int sc   = t & 3;
  const int cw   = sc ^ ((t >> 3) & 3);
  const int woff = srow * 32 + cw * 8;

  const float* gx = X + (size_t)(tile_m * 128 + srow) * DK + sc * 8;
  const float* ga = A + (size_t)(tile_n * 128 + srow) * DK + sc * 8;

  const int chA  = lg ^ ((l15 >> 1) & 3);
  const int aoff = (wr * 64 + l15) * 32 + chA * 8;
  const int boff = (wc * 64 + l15) * 32 + chA * 8;

  f32x4 acc[4][4] = {};

  auto load_tile = [&](int kt) {
    Stage s;
    const float* px = gx + kt * 32;
    const float* pa = ga + kt * 32;
    s.x0a = *(const float4*)(px);
    s.x0b = *(const float4*)(px + 4);
    s.x1a = *(const float4*)(px + (size_t)64 * DK);
    s.x1b = *(const float4*)(px + (size_t)64 * DK + 4);
    s.a0a = *(const float4*)(pa);
    s.a0b = *(const float4*)(pa + 4);
    s.a1a = *(const float4*)(pa + (size_t)64 * DK);
    s.a1b = *(const float4*)(pa + (size_t)64 * DK + 4);
    return s;
  };

  auto store_stage = [&](const Stage& s) {
    *(bf16x8*)(Xs + woff)            = pack8(s.x0a, s.x0b);
    *(bf16x8*)(Xs + woff + 64 * 32)  = pack8(s.x1a, s.x1b);
    *(bf16x8*)(As + woff)            = pack8(s.a0a, s.a0b);
    *(bf16x8*)(As + woff + 64 * 32)  = pack8(s.a1a, s.a1b);
  };

  auto compute = [&]() {
    bf16x8 af[4], bfr[4];
#pragma unroll
    for (int m = 0; m < 4; ++m)
      af[m] = *(const bf16x8*)(Xs + aoff + m * 16 * 32);
#pragma unroll
    for (int n = 0; n < 4; ++n)
      bfr[n] = *(const bf16x8*)(As + boff + n * 16 * 32);
#pragma unroll
    for (int m = 0; m < 4; ++m)
#pragma unroll
      for (int n = 0; n < 4; ++n)
        acc[m][n] = __builtin_amdgcn_mfma_f32_16x16x32_bf16(af[m], bfr[n],
                                                            acc[m][n], 0, 0, 0);
  };

  Stage sa = load_tile(0), sb;

  for (int kt = 0; kt < 128; kt += 2) {
    __syncthreads();
    store_stage(sa);
    sb = load_tile(kt + 1);
    __syncthreads();
    compute();
    __syncthreads();
    store_stage(sb);
    if (kt + 2 < 128) sa = load_tile(kt + 2);
    __syncthreads();
    compute();
  }

  float v[4][4];
#pragma unroll
  for (int m = 0; m < 4; ++m)
#pragma unroll
    for (int j = 0; j < 4; ++j) {
      float s = 0.f;
#pragma unroll
      for (int n = 0; n < 4; ++n) {
        float c = acc[m][n][j];
        s += c * c;
      }
      s += __shfl_xor(s, 1, 64);
      s += __shfl_xor(s, 2, 64);
      s += __shfl_xor(s, 4, 64);
      s += __shfl_xor(s, 8, 64);
      v[m][j] = s;
    }

  if (l15 == 0) {
#pragma unroll
    for (int m = 0; m < 4; ++m)
#pragma unroll
      for (int j = 0; j < 4; ++j)
        rowsum[wc][wr * 64 + m * 16 + lg * 4 + j] = v[m][j];
  }
  __syncthreads();

  if (t < 128) {
    float p = rowsum[0][t] + rowsum[1][t];
    atomicAdd(&out[tile_m * 128 + t], p);
  }
}

extern "C" void kernel_launch(void* const* d_in, const int* in_sizes, int n_in,
                              void* d_out, int out_size, void* d_ws, size_t ws_size,
                              hipStream_t stream) {
  const float* x = (const float*)d_in[0];
  const float* A = (const float*)d_in[1];
  float* out = (float*)d_out;

  hipMemsetAsync(out, 0, (size_t)out_size * sizeof(float), stream);

  if (ws_size >= WS_NEED) {
    __bf16* wsX = (__bf16*)d_ws;
    __bf16* wsW = wsX + X_ELEMS;
    hipLaunchKernelGGL(convX, dim3(2048), dim3(256), 0, stream, x, wsX);
    hipLaunchKernelGGL(convW, dim3(2048), dim3(256), 0, stream, A, wsW);
    hipLaunchKernelGGL(gemm9, dim3(512), dim3(512), 0, stream, wsX, wsW, out);
  } else {
    hipLaunchKernelGGL(gemm_rowsq, dim3(2048), dim3(256), 0, stream, x, A, out);
  }
}